// Round 6
// baseline (92.595 us; speedup 1.0000x reference)
//
#include <hip/hip_runtime.h>

// GaussianUpsampling: out[b,f,a] = sum_t softmax_t(-0.1*(t_f - c_t)^2) * hs[b,t,a]
//   c = cumsum(ds) - ds/2, t_f = f * h_mask[b,f]
// Measurement model (R4): dur_us includes ~58-64us harness poison/restore;
// kernel itself ~25-30us at R5 vs ~13us memory floor (64MB out + ~10MB fetch).
// R5 -> R6: residual attributed to per-block serial prologue (scan chain,
// 9 dependent binary-search probes, 3 barriers) x 4096 blocks.
//  - kFTile 16->32, 512-thread blocks (8 waves, wave q owns frames 4q..4q+3):
//    halves prologue instances; K only grows ~17->~21.
//  - __launch_bounds__(512,8) targets 64 VGPR -> 4 blocks/CU = 32 waves (100%).
//    VGPR diet: phase-B unroll x4->x2, 32-bit indexing (all buffers < 4GB).
//  - falsifier: regression => VGPR spill; revert to (512,7)/(256,7).

namespace {
constexpr int kB = 16;      // batch
constexpr int kT = 512;     // T_text
constexpr int kA = 256;     // adim
constexpr int kF = 4096;    // T_feats
constexpr float kDelta = 0.1f;
constexpr int kFTile = 32;  // frames per block
constexpr int kThreads = 512;
constexpr int kRadius = 10; // rel wt at cutoff: exp(-10)=4.5e-5
constexpr int kPad = 4;     // extra token padding each side
constexpr int kMaxK = 128;  // window cap; realistic K <= ~40
constexpr int kWStride = kFTile + 4;  // 36: float4 reads 16B-aligned; phase-A writes 2-way bank alias (free)
typedef float f32x4 __attribute__((ext_vector_type(4)));
}

__global__ __launch_bounds__(kThreads, 8) void upsample_kernel(
    const float* __restrict__ hs, const float* __restrict__ ds,
    const int* __restrict__ h_masks, const int* __restrict__ d_masks,
    float* __restrict__ out) {
  __shared__ __align__(16) float s_c[kT];
  __shared__ int s_dm[kT];
  __shared__ __align__(16) float s_w[kMaxK * kWStride];  // 18.4 KB
  __shared__ float s_t[kFTile];
  __shared__ float s_rsum[kFTile];
  __shared__ float s_wsum[8];

  const int id = blockIdx.x;
  const int b = id & 15;        // batch in low bits => same batch -> same XCD (id%8)
  const int f0 = (id >> 4) * kFTile;
  const int tid = threadIdx.x;
  const int wave = tid >> 6, lane = tid & 63;

  // --- fused token-center scan: thread t owns ds[t] (512 threads = kT) ---
  const float dso = ds[b * kT + tid];
  float incl = dso;
#pragma unroll
  for (int off = 1; off < 64; off <<= 1) {
    float u = __shfl_up(incl, off, 64);
    if (lane >= off) incl += u;
  }
  if (lane == 63) s_wsum[wave] = incl;

  s_dm[tid] = d_masks[b * kT + tid];

  const int g = tid >> 4;   // frame group 0..31
  const int l = tid & 15;   // lane within group
  const float tf = h_masks[b * kF + f0 + g] ? (float)(f0 + g) : 0.0f;
  __syncthreads();

  float base = 0.0f;
#pragma unroll
  for (int w = 0; w < 8; ++w)
    if (w < wave) base += s_wsum[w];
  s_c[tid] = base + incl - 0.5f * dso;  // excl-sum + ds/2
  if (l == 0) s_t[g] = tf;
  __syncthreads();

  // --- window selection (uniform across block) ---
  float tmin = s_t[0], tmax = s_t[0];
#pragma unroll
  for (int i = 1; i < kFTile; ++i) {
    tmin = fminf(tmin, s_t[i]);
    tmax = fmaxf(tmax, s_t[i]);
  }
  const float lo = tmin - (float)kRadius;
  const float hi = tmax + (float)kRadius;
  // fused dual binary search: independent probes overlap their LDS latency
  int alo = 0, elo = kT;   // lower_bound: first j with c[j] >= lo
  int ahi = 0, ehi = kT;   // upper_bound: first j with c[j] > hi
#pragma unroll
  for (int it = 0; it < 9; ++it) {
    const int m1 = (alo + elo) >> 1;
    const int m2 = (ahi + ehi) >> 1;
    const float c1 = s_c[m1];
    const float c2 = s_c[m2];
    if (alo < elo) { if (c1 < lo) alo = m1 + 1; else elo = m1; }
    if (ahi < ehi) { if (c2 <= hi) ahi = m2 + 1; else ehi = m2; }
  }
  int jlo = max(0, alo - kPad);
  int jhi = min(kT, ahi + kPad);
  int K = jhi - jlo;
  if (K > kMaxK) {  // keep the central (highest-weight) tokens
    jlo += (K - kMaxK) >> 1;
    jhi = jlo + kMaxK;
    K = kMaxK;
  }
  {  // pad K to a multiple of 4 with real in-range tokens (weights ~0 anyway)
    const int ext = (4 - (K & 3)) & 3;
    if (jhi + ext <= kT) jhi += ext; else jlo -= ext;
    K += ext;
  }

  // --- Phase A: windowed softmax weights into LDS [token][frame] ---
  float m = -1e38f;
  for (int jj = l; jj < K; jj += 16) {
    const int j = jlo + jj;
    const float d = tf - s_c[j];
    float e = -kDelta * d * d;
    if (!s_dm[j]) e = -1e30f;
    s_w[jj * kWStride + g] = e;
    m = fmaxf(m, e);
  }
#pragma unroll
  for (int off = 8; off >= 1; off >>= 1) m = fmaxf(m, __shfl_xor(m, off, 16));
  float ssum = 0.0f;
  for (int jj = l; jj < K; jj += 16) {
    const float w = __expf(s_w[jj * kWStride + g] - m);
    s_w[jj * kWStride + g] = w;
    ssum += w;
  }
#pragma unroll
  for (int off = 8; off >= 1; off >>= 1) ssum += __shfl_xor(ssum, off, 16);
  if (l == 0) s_rsum[g] = 1.0f / ssum;
  __syncthreads();

  // --- Phase B: windowed einsum, unroll x2 (K % 2 == 0) ---
  const int q = wave;              // frame quad 4q..4q+3 (wave-uniform -> LDS broadcast)
  const int ch = lane << 2;        // float4 channel slice, coalesced
  const float* hp = hs + (b * kT + jlo) * kA + ch;   // 32-bit offsets: hs < 16M elems
  const float* wp = s_w + 4 * q;
  float acc[4][4];
#pragma unroll
  for (int i = 0; i < 4; ++i)
#pragma unroll
    for (int k = 0; k < 4; ++k) acc[i][k] = 0.0f;

  for (int jj = 0; jj < K; jj += 2) {
    const float4 h0 = *reinterpret_cast<const float4*>(hp);
    const float4 h1 = *reinterpret_cast<const float4*>(hp + kA);
    const float4 w0 = *reinterpret_cast<const float4*>(wp);
    const float4 w1 = *reinterpret_cast<const float4*>(wp + kWStride);
    const float hf0[4] = {h0.x, h0.y, h0.z, h0.w};
    const float hf1[4] = {h1.x, h1.y, h1.z, h1.w};
    const float wf0[4] = {w0.x, w0.y, w0.z, w0.w};
    const float wf1[4] = {w1.x, w1.y, w1.z, w1.w};
#pragma unroll
    for (int i = 0; i < 4; ++i)
#pragma unroll
      for (int k = 0; k < 4; ++k) {
        acc[i][k] += wf0[i] * hf0[k];
        acc[i][k] += wf1[i] * hf1[k];
      }
    hp += 2 * kA;
    wp += 2 * kWStride;
  }

  float* ob = out + ((unsigned)(b * kF + f0 + 4 * q)) * kA + ch;  // out < 17M elems
#pragma unroll
  for (int i = 0; i < 4; ++i) {
    const float r = s_rsum[4 * q + i];
    f32x4 o;
    o.x = acc[i][0] * r; o.y = acc[i][1] * r;
    o.z = acc[i][2] * r; o.w = acc[i][3] * r;
    __builtin_nontemporal_store(o, reinterpret_cast<f32x4*>(ob + i * kA));
  }
}

extern "C" void kernel_launch(void* const* d_in, const int* in_sizes, int n_in,
                              void* d_out, int out_size, void* d_ws, size_t ws_size,
                              hipStream_t stream) {
  const float* hs = (const float*)d_in[0];   // (16, 512, 256) fp32
  const float* ds = (const float*)d_in[1];   // (16, 512) fp32
  const int* h_masks = (const int*)d_in[2];  // (16, 4096) bool -> int32
  const int* d_masks = (const int*)d_in[3];  // (16, 512) bool -> int32
  float* out = (float*)d_out;                // (16, 4096, 256) fp32

  upsample_kernel<<<kB * (kF / kFTile), kThreads, 0, stream>>>(hs, ds, h_masks, d_masks, out);
}

// Round 7
// 90.989 us; speedup vs baseline: 1.0177x; 1.0177x over previous
//
#include <hip/hip_runtime.h>

// GaussianUpsampling: out[b,f,a] = sum_t softmax_t(-0.1*(t_f - c_t)^2) * hs[b,t,a]
//   c = cumsum(ds) - ds/2, t_f = f * h_mask[b,f]
// Measurement model (R6 revision): harness poison/restore ~72-77us of dur_us
// (268MB ws-fill 43 + 67MB out-fill 11 + ~34MB input restore 11 + gaps).
// Kernel ~16-18us vs compulsory-traffic floor 98MB/6.3TBps ~= 15.6us:
//   FETCH ~33MB == hs read exactly once (L2 absorbs windowed re-reads, R2 PMC),
//   WRITE ~65MB == output. Both compulsory.
// R6 -> R7: revert to R5's best config (256 thr, kFTile 16, unroll x4);
// replace 9-probe dependent binary search (~1100 serial cyc/block) with
// ballot-based bounds: post-scan each thread holds its 2 centers in regs;
// jlo = count(c < lo), jhi = count(c <= hi) via __ballot/popcount (valid:
// cumsum nondecreasing). Same 3 barriers, no dependent LDS probe chain.

namespace {
constexpr int kB = 16;      // batch
constexpr int kT = 512;     // T_text
constexpr int kA = 256;     // adim
constexpr int kF = 4096;    // T_feats
constexpr float kDelta = 0.1f;
constexpr int kFTile = 16;  // frames per block
constexpr int kRadius = 10; // rel wt at cutoff exp(-10)=4.5e-5
constexpr int kPad = 4;     // extra token padding each side
constexpr int kMaxK = 128;  // window cap; realistic K <= ~40
constexpr int kWStride = kFTile + 4;  // [token][frame]: float4 reads 16B-aligned; 2-way bank alias free
typedef float f32x4 __attribute__((ext_vector_type(4)));
}

__global__ __launch_bounds__(256, 7) void upsample_kernel(
    const float* __restrict__ hs, const float* __restrict__ ds,
    const int* __restrict__ h_masks, const int* __restrict__ d_masks,
    float* __restrict__ out) {
  __shared__ __align__(16) float s_c[kT];
  __shared__ int s_dm[kT];
  __shared__ __align__(16) float s_w[kMaxK * kWStride];  // 10 KB
  __shared__ float s_t[kFTile];
  __shared__ float s_rsum[kFTile];
  __shared__ float s_wsum[4];
  __shared__ int s_cnt[8];

  const int id = blockIdx.x;
  const int b = id & 15;        // batch in low bits => same batch -> same XCD (id%8)
  const int f0 = (id >> 4) * kFTile;
  const int tid = threadIdx.x;
  const int wave = tid >> 6, lane = tid & 63;

  // --- fused token-center scan: thread t owns ds[2t], ds[2t+1] ---
  const float2 dsv = *reinterpret_cast<const float2*>(ds + b * kT + 2 * tid);
  const float psum = dsv.x + dsv.y;
  float incl = psum;
#pragma unroll
  for (int off = 1; off < 64; off <<= 1) {
    float u = __shfl_up(incl, off, 64);
    if (lane >= off) incl += u;
  }
  if (lane == 63) s_wsum[wave] = incl;

  for (int j = tid; j < kT; j += 256) s_dm[j] = d_masks[b * kT + j];

  const int g = tid >> 4;   // frame group 0..15
  const int l = tid & 15;   // lane within group
  const float tf = h_masks[b * kF + f0 + g] ? (float)(f0 + g) : 0.0f;
  if (l == 0) s_t[g] = tf;
  __syncthreads();

  float base = 0.0f;
#pragma unroll
  for (int w = 0; w < 4; ++w)
    if (w < wave) base += s_wsum[w];
  const float excl = base + incl - psum;
  const float c0 = excl + 0.5f * dsv.x;
  const float c1 = excl + dsv.x + 0.5f * dsv.y;
  s_c[2 * tid] = c0;
  s_c[2 * tid + 1] = c1;

  // --- window bounds via ballot (no dependent LDS probe chain) ---
  float tmin = s_t[0], tmax = s_t[0];
#pragma unroll
  for (int i = 1; i < kFTile; ++i) {
    tmin = fminf(tmin, s_t[i]);
    tmax = fmaxf(tmax, s_t[i]);
  }
  const float lo = tmin - (float)kRadius;
  const float hi = tmax + (float)kRadius;
  const unsigned long long blo0 = __ballot(c0 < lo);
  const unsigned long long blo1 = __ballot(c1 < lo);
  const unsigned long long bhi0 = __ballot(c0 <= hi);
  const unsigned long long bhi1 = __ballot(c1 <= hi);
  if (lane == 0) {
    s_cnt[wave]     = __popcll(blo0) + __popcll(blo1);
    s_cnt[4 + wave] = __popcll(bhi0) + __popcll(bhi1);
  }
  __syncthreads();

  const int alo = s_cnt[0] + s_cnt[1] + s_cnt[2] + s_cnt[3];  // lower_bound(lo)
  const int ahi = s_cnt[4] + s_cnt[5] + s_cnt[6] + s_cnt[7];  // upper_bound(hi)
  int jlo = max(0, alo - kPad);
  int jhi = min(kT, ahi + kPad);
  int K = jhi - jlo;
  if (K > kMaxK) {  // keep the central (highest-weight) tokens
    jlo += (K - kMaxK) >> 1;
    jhi = jlo + kMaxK;
    K = kMaxK;
  }
  {  // pad K to a multiple of 4 with real in-range tokens (weights ~0 anyway)
    const int ext = (4 - (K & 3)) & 3;
    if (jhi + ext <= kT) jhi += ext; else jlo -= ext;
    K += ext;
  }

  // --- Phase A: windowed softmax weights into LDS [token][frame] ---
  float m = -1e38f;
  for (int jj = l; jj < K; jj += 16) {
    const int j = jlo + jj;
    const float d = tf - s_c[j];
    float e = -kDelta * d * d;
    if (!s_dm[j]) e = -1e30f;
    s_w[jj * kWStride + g] = e;
    m = fmaxf(m, e);
  }
#pragma unroll
  for (int off = 8; off >= 1; off >>= 1) m = fmaxf(m, __shfl_xor(m, off, 16));
  float ssum = 0.0f;
  for (int jj = l; jj < K; jj += 16) {
    const float w = __expf(s_w[jj * kWStride + g] - m);
    s_w[jj * kWStride + g] = w;
    ssum += w;
  }
#pragma unroll
  for (int off = 8; off >= 1; off >>= 1) ssum += __shfl_xor(ssum, off, 16);
  if (l == 0) s_rsum[g] = 1.0f / ssum;
  __syncthreads();

  // --- Phase B: windowed einsum, unroll x4 (K % 4 == 0) ---
  const int q = tid >> 6;          // frame quad (wave-uniform -> LDS broadcast)
  const int ch = (tid & 63) << 2;  // float4 channel slice, coalesced
  const float* hp = hs + (b * kT + jlo) * kA + ch;
  const float* wp = s_w + 4 * q;
  float acc[4][4];
#pragma unroll
  for (int i = 0; i < 4; ++i)
#pragma unroll
    for (int k = 0; k < 4; ++k) acc[i][k] = 0.0f;

  for (int jj = 0; jj < K; jj += 4) {
    const float4 h0 = *reinterpret_cast<const float4*>(hp);
    const float4 h1 = *reinterpret_cast<const float4*>(hp + kA);
    const float4 h2 = *reinterpret_cast<const float4*>(hp + 2 * kA);
    const float4 h3 = *reinterpret_cast<const float4*>(hp + 3 * kA);
    const float4 w0 = *reinterpret_cast<const float4*>(wp);
    const float4 w1 = *reinterpret_cast<const float4*>(wp + kWStride);
    const float4 w2 = *reinterpret_cast<const float4*>(wp + 2 * kWStride);
    const float4 w3 = *reinterpret_cast<const float4*>(wp + 3 * kWStride);
    const float hf0[4] = {h0.x, h0.y, h0.z, h0.w};
    const float hf1[4] = {h1.x, h1.y, h1.z, h1.w};
    const float hf2[4] = {h2.x, h2.y, h2.z, h2.w};
    const float hf3[4] = {h3.x, h3.y, h3.z, h3.w};
    const float wf0[4] = {w0.x, w0.y, w0.z, w0.w};
    const float wf1[4] = {w1.x, w1.y, w1.z, w1.w};
    const float wf2[4] = {w2.x, w2.y, w2.z, w2.w};
    const float wf3[4] = {w3.x, w3.y, w3.z, w3.w};
#pragma unroll
    for (int i = 0; i < 4; ++i)
#pragma unroll
      for (int k = 0; k < 4; ++k) {
        acc[i][k] += wf0[i] * hf0[k];
        acc[i][k] += wf1[i] * hf1[k];
        acc[i][k] += wf2[i] * hf2[k];
        acc[i][k] += wf3[i] * hf3[k];
      }
    hp += 4 * kA;
    wp += 4 * kWStride;
  }

  float* ob = out + (unsigned)(b * kF + f0 + 4 * q) * kA + ch;
#pragma unroll
  for (int i = 0; i < 4; ++i) {
    const float r = s_rsum[4 * q + i];
    f32x4 o;
    o.x = acc[i][0] * r; o.y = acc[i][1] * r;
    o.z = acc[i][2] * r; o.w = acc[i][3] * r;
    __builtin_nontemporal_store(o, reinterpret_cast<f32x4*>(ob + i * kA));
  }
}

extern "C" void kernel_launch(void* const* d_in, const int* in_sizes, int n_in,
                              void* d_out, int out_size, void* d_ws, size_t ws_size,
                              hipStream_t stream) {
  const float* hs = (const float*)d_in[0];   // (16, 512, 256) fp32
  const float* ds = (const float*)d_in[1];   // (16, 512) fp32
  const int* h_masks = (const int*)d_in[2];  // (16, 4096) bool -> int32
  const int* d_masks = (const int*)d_in[3];  // (16, 512) bool -> int32
  float* out = (float*)d_out;                // (16, 4096, 256) fp32

  upsample_kernel<<<kB * (kF / kFTile), 256, 0, stream>>>(hs, ds, h_masks, d_masks, out);
}